// Round 3
// baseline (104.988 us; speedup 1.0000x reference)
//
#include <hip/hip_runtime.h>

#define BQ   15      // queries
#define NIMG 40      // 15 queries + 25 supports, concatenated
#define CH   64
#define HW   21
#define P    441     // 21*21
#define WIN  11
#define OH   11
#define OP   121     // 11*11

// Gaussian window (sigma=1.5, 11 taps), compile-time constant.
__device__ __forceinline__ float Wf(int a) {
    constexpr float w[WIN] = {
        0.0010283804f, 0.0075988025f, 0.0360007770f, 0.1093606993f,
        0.2130055427f, 0.2660117290f, 0.2130055427f, 0.1093606993f,
        0.0360007770f, 0.0075988025f, 0.0010283804f};
    return w[a];
}

// ---------------------------------------------------------------------------
// prep: normalize over channels + transpose (img, P, CH) -> tn (img, CH, P)
// grid (40, 7), block 256. Block (0,0) also zeroes d_out (pairs runs later
// in stream order, so its atomics are safe).
// ---------------------------------------------------------------------------
__global__ void __launch_bounds__(256) prep_kernel(const float* __restrict__ x1,
                                                   const float* __restrict__ x2,
                                                   float* __restrict__ tn,
                                                   float* __restrict__ out) {
    if (blockIdx.x == 0 && blockIdx.y == 0 && threadIdx.x < BQ * 5)
        out[threadIdx.x] = 0.f;

    int img = blockIdx.x;           // 0..39
    int p0  = blockIdx.y * 63;      // 7 chunks of 63 = 441
    const float* src = (img < BQ) ? (x1 + (size_t)img * P * CH)
                                  : (x2 + (size_t)(img - BQ) * P * CH);
    float* dst = tn + (size_t)img * CH * P;

    __shared__ float tile[63 * 65];
    __shared__ float invn[63];

    for (int i = threadIdx.x; i < 63 * CH; i += 256) {
        int p = i >> 6, c = i & 63;
        tile[p * 65 + c] = src[(size_t)p0 * CH + i];   // fully coalesced
    }
    __syncthreads();
    if (threadIdx.x < 63) {
        int p = threadIdx.x;
        float s = 0.f;
#pragma unroll
        for (int c = 0; c < CH; ++c) { float v = tile[p * 65 + c]; s += v * v; }
        invn[p] = rsqrtf(s);
    }
    __syncthreads();
    for (int i = threadIdx.x; i < 63 * CH; i += 256) {
        int c = i / 63, p = i - c * 63;
        dst[(size_t)c * P + p0 + p] = tile[p * 65 + c] * invn[p];
    }
}

// ---------------------------------------------------------------------------
// stats: per channel-image ic, separable blur of x and x^2 -> mu, sq (121).
// Register-column scheme: lane = (k, j), k = lane/21 channel-within-wave,
// j = column. H-blur in registers, W-blur via __shfl. No LDS.
// grid 214 blocks x 256 (12 channel-images per block, 3 per wave).
// ---------------------------------------------------------------------------
__global__ void __launch_bounds__(256) stats_kernel(const float* __restrict__ tn,
                                                    float* __restrict__ mu,
                                                    float* __restrict__ sq) {
    int lane = threadIdx.x & 63, w = threadIdx.x >> 6;
    int k = lane / HW, j = lane - k * HW;           // k==3 (lane 63) invalid
    int ic = blockIdx.x * 12 + w * 3 + k;
    bool vch = (k < 3) && (ic < NIMG * CH);
    const float* X = tn + (size_t)(vch ? ic : 0) * P;

    float t1[OH], t2[OH];
#pragma unroll
    for (int r = 0; r < OH; ++r) { t1[r] = 0.f; t2[r] = 0.f; }
#pragma unroll
    for (int i = 0; i < HW; ++i) {
        float x = vch ? X[i * HW + j] : 0.f;
        float xx = x * x;
#pragma unroll
        for (int r = 0; r < OH; ++r) {
            int a = i - r;
            if (a >= 0 && a < WIN) {
                t1[r] = fmaf(Wf(a), x, t1[r]);
                t2[r] = fmaf(Wf(a), xx, t2[r]);
            }
        }
    }
    // W-blur via cross-lane shuffles (columns j..j+10 live on lanes lane..lane+10)
    float o1[OH], o2[OH];
#pragma unroll
    for (int r = 0; r < OH; ++r) {
        float a1 = Wf(0) * t1[r];
        float a2 = Wf(0) * t2[r];
#pragma unroll
        for (int a = 1; a < WIN; ++a) {
            a1 = fmaf(Wf(a), __shfl(t1[r], lane + a), a1);
            a2 = fmaf(Wf(a), __shfl(t2[r], lane + a), a2);
        }
        o1[r] = a1; o2[r] = a2;
    }
    if (vch && j < OH) {
        size_t o = (size_t)ic * OP + j;
#pragma unroll
        for (int r = 0; r < OH; ++r) {
            mu[o + r * OH] = o1[r];
            sq[o + r * OH] = o2[r];
        }
    }
}

// ---------------------------------------------------------------------------
// pairs: grid (375, 6), block 256; 12 channels per block (3 per wave),
// register-column H-blur + shuffle W-blur of X*Y, then SSIM combine with
// precomputed one-sided stats. One atomic per block.
// ---------------------------------------------------------------------------
__global__ void __launch_bounds__(256) pairs_kernel(const float* __restrict__ tn,
                                                    const float* __restrict__ mu,
                                                    const float* __restrict__ sq,
                                                    float* __restrict__ out) {
    int pair = blockIdx.x;          // 0..374
    int b    = pair / 25;
    int rem  = pair - b * 25;       // support image index (n*5 + si)
    int lane = threadIdx.x & 63, w = threadIdx.x >> 6;
    int k = lane / HW, j = lane - k * HW;
    int c = blockIdx.y * 12 + w * 3 + k;
    bool vch = (k < 3) && (c < CH);
    int cs = vch ? c : 0;

    const float* X = tn + ((size_t)b * CH + cs) * P;
    const float* Y = tn + ((size_t)(BQ + rem) * CH + cs) * P;

    float t1[OH];
#pragma unroll
    for (int r = 0; r < OH; ++r) t1[r] = 0.f;
#pragma unroll
    for (int i = 0; i < HW; ++i) {
        float xy = vch ? X[i * HW + j] * Y[i * HW + j] : 0.f;
#pragma unroll
        for (int r = 0; r < OH; ++r) {
            int a = i - r;
            if (a >= 0 && a < WIN) t1[r] = fmaf(Wf(a), xy, t1[r]);
        }
    }
    float o[OH];
#pragma unroll
    for (int r = 0; r < OH; ++r) {
        float a1 = Wf(0) * t1[r];
#pragma unroll
        for (int a = 1; a < WIN; ++a)
            a1 = fmaf(Wf(a), __shfl(t1[r], lane + a), a1);
        o[r] = a1;
    }

    const float C1 = 1e-4f, C2 = 9e-4f;
    float part = 0.f;
    if (vch && j < OH) {
        size_t oq = ((size_t)b * CH + c) * OP + j;
        size_t os = ((size_t)(BQ + rem) * CH + c) * OP + j;
#pragma unroll
        for (int r = 0; r < OH; ++r) {
            float m1 = mu[oq + r * OH], m2 = mu[os + r * OH];
            float v1 = sq[oq + r * OH] - m1 * m1;
            float v2 = sq[os + r * OH] - m2 * m2;
            float cov = o[r] - m1 * m2;
            part += ((2.f * m1 * m2 + C1) * (2.f * cov + C2)) /
                    ((m1 * m1 + m2 * m2 + C1) * (v1 + v2 + C2));
        }
    }

    // wave butterfly + cross-wave LDS + one atomic
#pragma unroll
    for (int off = 32; off > 0; off >>= 1) part += __shfl_down(part, off, 64);
    __shared__ float ws4[4];
    if ((threadIdx.x & 63) == 0) ws4[w] = part;
    __syncthreads();
    if (threadIdx.x == 0) {
        int n = rem / 5;
        atomicAdd(&out[b * 5 + n],
                  (ws4[0] + ws4[1] + ws4[2] + ws4[3]) * (1.0f / (CH * OP)));
    }
}

extern "C" void kernel_launch(void* const* d_in, const int* in_sizes, int n_in,
                              void* d_out, int out_size, void* d_ws, size_t ws_size,
                              hipStream_t stream) {
    const float* x1 = (const float*)d_in[0];   // (15, 441, 64)
    const float* x2 = (const float*)d_in[1];   // (5, 5, 441, 64)
    float* out = (float*)d_out;                // (15, 5)
    float* ws  = (float*)d_ws;

    float* tn = ws;                                  // 40*64*441
    float* mu = tn + (size_t)NIMG * CH * P;          // 2560*121
    float* sq = mu + (size_t)NIMG * CH * OP;         // 2560*121

    prep_kernel<<<dim3(NIMG, 7), 256, 0, stream>>>(x1, x2, tn, out);
    stats_kernel<<<(NIMG * CH + 11) / 12, 256, 0, stream>>>(tn, mu, sq);
    pairs_kernel<<<dim3(375, 6), 256, 0, stream>>>(tn, mu, sq, out);
}

// Round 4
// 98.621 us; speedup vs baseline: 1.0646x; 1.0646x over previous
//
#include <hip/hip_runtime.h>

#define BQ   15      // queries
#define NIMG 40      // 15 queries + 25 supports, concatenated
#define CH   64
#define HW   21
#define P    441     // 21*21
#define WIN  11
#define OH   11
#define OP   121     // 11*11
#define TP   231     // 11*21

// Gaussian window (sigma=1.5, 11 taps), compile-time constant.
__device__ __forceinline__ float Wf(int a) {
    constexpr float w[WIN] = {
        0.0010283804f, 0.0075988025f, 0.0360007770f, 0.1093606993f,
        0.2130055427f, 0.2660117290f, 0.2130055427f, 0.1093606993f,
        0.0360007770f, 0.0075988025f, 0.0010283804f};
    return w[a];
}

// ---------------------------------------------------------------------------
// prep: normalize over channels + transpose (img, P, CH) -> tn (img, CH, P)
// grid (40, 7), block 256. Block (0,0) also zeroes d_out (pairs runs later
// in stream order, so its atomics are safe).
// ---------------------------------------------------------------------------
__global__ void __launch_bounds__(256) prep_kernel(const float* __restrict__ x1,
                                                   const float* __restrict__ x2,
                                                   float* __restrict__ tn,
                                                   float* __restrict__ out) {
    if (blockIdx.x == 0 && blockIdx.y == 0 && threadIdx.x < BQ * 5)
        out[threadIdx.x] = 0.f;

    int img = blockIdx.x;           // 0..39
    int p0  = blockIdx.y * 63;      // 7 chunks of 63 = 441
    const float* src = (img < BQ) ? (x1 + (size_t)img * P * CH)
                                  : (x2 + (size_t)(img - BQ) * P * CH);
    float* dst = tn + (size_t)img * CH * P;

    __shared__ float tile[63 * 65];
    __shared__ float invn[63];

    for (int i = threadIdx.x; i < 63 * CH; i += 256) {
        int p = i >> 6, c = i & 63;
        tile[p * 65 + c] = src[(size_t)p0 * CH + i];   // fully coalesced
    }
    __syncthreads();
    if (threadIdx.x < 63) {
        int p = threadIdx.x;
        float s = 0.f;
#pragma unroll
        for (int c = 0; c < CH; ++c) { float v = tile[p * 65 + c]; s += v * v; }
        invn[p] = rsqrtf(s);
    }
    __syncthreads();
    for (int i = threadIdx.x; i < 63 * CH; i += 256) {
        int c = i / 63, p = i - c * 63;
        dst[(size_t)c * P + p0 + p] = tile[p * 65 + c] * invn[p];
    }
}

// ---------------------------------------------------------------------------
// stats: per channel-image, separable blur of x and x^2 -> mu, sq (121 each)
// grid 320, block 256; 8 channels per block. Row blur uses addr = t + 21a.
// LDS layout per channel (stride 920): [0,441) data, [448,679) t1, [684,915) t2
// ---------------------------------------------------------------------------
__global__ void __launch_bounds__(256) stats_kernel(const float* __restrict__ tn,
                                                    float* __restrict__ mu,
                                                    float* __restrict__ sq) {
    __shared__ float lds[8 * 920];
    int cb = blockIdx.x * 8;        // global channel-image base, < 2560

    for (int i = threadIdx.x; i < 8 * P; i += 256) {
        int k = i / P, t = i - k * P;
        lds[k * 920 + t] = tn[(size_t)cb * P + i];
    }
    __syncthreads();
    for (int i = threadIdx.x; i < 8 * TP; i += 256) {
        int k = i / TP, t = i - k * TP;
        const float* x = lds + k * 920;
        float a1 = 0.f, a2 = 0.f;
#pragma unroll
        for (int a = 0; a < WIN; ++a) {
            float v = x[t + 21 * a];              // sequential addresses
            a1 = fmaf(Wf(a), v, a1);
            a2 = fmaf(Wf(a) * v, v, a2);
        }
        lds[k * 920 + 448 + t] = a1;
        lds[k * 920 + 684 + t] = a2;
    }
    __syncthreads();
    for (int i = threadIdx.x; i < 8 * OP; i += 256) {
        int k = i / OP, t = i - k * OP;
        int r = t / OH, cc = t - r * OH;
        int b0 = r * HW + cc;
        const float* t1 = lds + k * 920 + 448;
        const float* t2 = lds + k * 920 + 684;
        float a1 = 0.f, a2 = 0.f;
#pragma unroll
        for (int a = 0; a < WIN; ++a) {
            a1 = fmaf(Wf(a), t1[b0 + a], a1);
            a2 = fmaf(Wf(a), t2[b0 + a], a2);
        }
        size_t o = (size_t)(cb + k) * OP + t;
        mu[o] = a1;
        sq[o] = a2;
    }
}

// ---------------------------------------------------------------------------
// pairs: grid (375, 8), block 256; 8 channels per block, 3 barriers total.
// LDS per channel (stride 684): [0,441) xy, [448,679) row-blurred t1.
// 21.9 KB LDS -> 7 blocks/CU occupancy.
// ---------------------------------------------------------------------------
__global__ void __launch_bounds__(256) pairs_kernel(const float* __restrict__ tn,
                                                    const float* __restrict__ mu,
                                                    const float* __restrict__ sq,
                                                    float* __restrict__ out) {
    __shared__ float lds[8 * 684];
    __shared__ float ws4[4];

    int pair = blockIdx.x;          // 0..374
    int b    = pair / 25;
    int rem  = pair - b * 25;       // support image index (n*5 + si)
    int cb   = blockIdx.y * 8;      // channel base

    const float* X = tn + ((size_t)b * CH + cb) * P;
    const float* Y = tn + ((size_t)(BQ + rem) * CH + cb) * P;

    for (int i = threadIdx.x; i < 8 * P; i += 256) {
        int k = i / P, t = i - k * P;
        lds[k * 684 + t] = X[i] * Y[i];
    }
    __syncthreads();
    for (int i = threadIdx.x; i < 8 * TP; i += 256) {
        int k = i / TP, t = i - k * TP;
        const float* x = lds + k * 684;
        float a1 = 0.f;
#pragma unroll
        for (int a = 0; a < WIN; ++a) a1 = fmaf(Wf(a), x[t + 21 * a], a1);
        lds[k * 684 + 448 + t] = a1;
    }
    __syncthreads();

    const float C1 = 1e-4f, C2 = 9e-4f;
    size_t oq = ((size_t)b * CH + cb) * OP;
    size_t os = ((size_t)(BQ + rem) * CH + cb) * OP;
    float part = 0.f;
    for (int i = threadIdx.x; i < 8 * OP; i += 256) {
        int k = i / OP, t = i - k * OP;
        int r = t / OH, cc = t - r * OH;
        const float* t1 = lds + k * 684 + 448;
        float sxy = 0.f;
#pragma unroll
        for (int a = 0; a < WIN; ++a) sxy = fmaf(Wf(a), t1[r * HW + cc + a], sxy);
        float m1 = mu[oq + i], m2 = mu[os + i];
        float v1 = sq[oq + i] - m1 * m1;
        float v2 = sq[os + i] - m2 * m2;
        float cov = sxy - m1 * m2;
        part += ((2.f * m1 * m2 + C1) * (2.f * cov + C2)) /
                ((m1 * m1 + m2 * m2 + C1) * (v1 + v2 + C2));
    }

    // block reduce: 4 waves of 64
#pragma unroll
    for (int off = 32; off > 0; off >>= 1) part += __shfl_down(part, off, 64);
    if ((threadIdx.x & 63) == 0) ws4[threadIdx.x >> 6] = part;
    __syncthreads();
    if (threadIdx.x == 0) {
        int n = rem / 5;
        atomicAdd(&out[b * 5 + n],
                  (ws4[0] + ws4[1] + ws4[2] + ws4[3]) * (1.0f / (CH * OP)));
    }
}

extern "C" void kernel_launch(void* const* d_in, const int* in_sizes, int n_in,
                              void* d_out, int out_size, void* d_ws, size_t ws_size,
                              hipStream_t stream) {
    const float* x1 = (const float*)d_in[0];   // (15, 441, 64)
    const float* x2 = (const float*)d_in[1];   // (5, 5, 441, 64)
    float* out = (float*)d_out;                // (15, 5)
    float* ws  = (float*)d_ws;

    float* tn = ws;                                  // 40*64*441
    float* mu = tn + (size_t)NIMG * CH * P;          // 2560*121
    float* sq = mu + (size_t)NIMG * CH * OP;         // 2560*121

    prep_kernel<<<dim3(NIMG, 7), 256, 0, stream>>>(x1, x2, tn, out);
    stats_kernel<<<NIMG * CH / 8, 256, 0, stream>>>(tn, mu, sq);
    pairs_kernel<<<dim3(375, 8), 256, 0, stream>>>(tn, mu, sq, out);
}